// Round 7
// baseline (9140.988 us; speedup 1.0000x reference)
//
#include <hip/hip_runtime.h>

// LSTM: S=4096, I=64, H=1024, O=1, fp32.
// Persistent cooperative kernel. Round-15 (this round): NBLK=64, HPB=16.
//   Sessions' verdict so far: r0's protocol is a sharp local optimum (r1
//   fan-out +18%, r2 wave dataflow +103%, r3 depth-2 poll +13%, r4 chunk
//   flags +25%, r5 tag decouple +171%; r6 restore re-validated 8039us).
//   FETCH_SIZE ~56KB/step ~= 128 lines x 8 XCD refetches => directory-style
//   invalidate+refetch storm per step; cost scales with participant count.
//   The ONE untouched axis: number of blocks. This round halves participants
//   (64 blocks x 512 thr, 16 h/block, 2 h/wave) with ZERO protocol change:
//   same tagged 8B atoms, same conditional 1-in-flight poll (each thread
//   still polls slots t and t+512), same single barrier, same wave-0 gather;
//   publish is lanes 0..15 -> one 128B (2 full lines) store.
//   WRITE_SIZE invariant: 64 x 128B x 4096 = 32768 KB.
//   Per-thread weights double -> 34 named float4 (two LDS staging passes;
//   LDS-sourced reads are not remat-able -> RA keeps them in VGPRs, r9).
//   Decision rule (pre-committed): >= 8000us => participant count is not a
//   lever; restore r0 and declare structural roofline.

#define SEQ_LEN 4096
#define HID 1024
#define NBLK 64
#define TPB 512
#define HPB 16     // h-indices per block (two per wave)

__device__ __forceinline__ float fast_sigmoid(float x) {
    return __builtin_amdgcn_rcpf(1.0f + __builtin_amdgcn_exp2f(-1.4426950408889634f * x));
}
__device__ __forceinline__ float fast_tanh(float x) {
    return fmaf(-2.0f, __builtin_amdgcn_rcpf(1.0f + __builtin_amdgcn_exp2f(2.8853900817779268f * x)), 1.0f);
}

// ws: unsigned long long slots[2][1024]. {tag:32 | fp32 bits}. Zero-init:
// buffer0 tag0/val0 == h_0 = 0 (correct); buffer1 receives odd tags.
__global__ void lstm_init_kernel(unsigned long long* ws) {
    int t = threadIdx.x;
    #pragma unroll
    for (int k = 0; k < 8; ++k) ws[t + 256 * k] = 0ull;
}

__global__ __launch_bounds__(TPB, 1) void lstm_persistent_kernel(
    const float* __restrict__ input,   // [4096][64]
    const float* __restrict__ W_ih,    // [4096][64]
    const float* __restrict__ W_hh,    // [4096][1024]
    const float* __restrict__ b_ih,    // [4096]
    const float* __restrict__ b_hh,    // [4096]
    const float* __restrict__ W_lin,   // [1][1024]
    const float* __restrict__ b_lin,   // [1]
    float* __restrict__ out,           // [1]
    unsigned long long* __restrict__ ws)
{
    const int t   = threadIdx.x;
    const int b   = blockIdx.x;
    const int w   = t >> 6;      // wave in block (0..7)
    const int l   = t & 63;      // lane
    const int grp = l >> 4;      // gate q (i,f,g,o)
    const int sl  = l & 15;      // sub-lane within gate group
    const int j0  = HPB * b + w;      // first owned h index  (k = w)
    const int j1  = HPB * b + w + 8;  // second owned h index (k = w+8)
    const int row0 = grp * HID + j0;
    const int row1 = grp * HID + j1;

    unsigned long long* slot0 = ws;          // even tags
    unsigned long long* slot1 = ws + HID;    // odd tags

    __shared__ float4 wlds4[17 * TPB];       // 136 KB weight staging (reused 2x)
    __shared__ float  hs[2][HID];            // double-buffered h (8 KB)
    __shared__ unsigned long long pub[HPB];  // tagged intra-block handoff
    __shared__ float  red[8];

    // ---- staging pass A: rows for j0 ----
    {
        const float4* Whh4 = (const float4*)(W_hh + (size_t)row0 * HID);
        #pragma unroll
        for (int c = 0; c < 16; ++c)
            wlds4[c * TPB + t] = Whh4[sl + 16 * c];     // W_hh[row0][64c+4sl..+3]
        wlds4[16 * TPB + t] = ((const float4*)(W_ih + (size_t)row0 * 64))[sl];
    }
    float bias0[4], bias1[4];
    #pragma unroll
    for (int q = 0; q < 4; ++q) {
        bias0[q] = b_ih[q * HID + j0] + b_hh[q * HID + j0];
        bias1[q] = b_ih[q * HID + j1] + b_hh[q * HID + j1];
    }
    if (t < HPB) pub[t] = 0ull;
    __syncthreads();   // pass-A staged (also: pub initialized)

    // ---- LDS -> named registers, set A (j0). Not remat-able -> VGPRs. ----
    const float4 W0  = wlds4[ 0 * TPB + t];
    const float4 W1  = wlds4[ 1 * TPB + t];
    const float4 W2  = wlds4[ 2 * TPB + t];
    const float4 W3  = wlds4[ 3 * TPB + t];
    const float4 W4  = wlds4[ 4 * TPB + t];
    const float4 W5  = wlds4[ 5 * TPB + t];
    const float4 W6  = wlds4[ 6 * TPB + t];
    const float4 W7  = wlds4[ 7 * TPB + t];
    const float4 W8  = wlds4[ 8 * TPB + t];
    const float4 W9  = wlds4[ 9 * TPB + t];
    const float4 W10 = wlds4[10 * TPB + t];
    const float4 W11 = wlds4[11 * TPB + t];
    const float4 W12 = wlds4[12 * TPB + t];
    const float4 W13 = wlds4[13 * TPB + t];
    const float4 W14 = wlds4[14 * TPB + t];
    const float4 W15 = wlds4[15 * TPB + t];
    const float4 W16 = wlds4[16 * TPB + t];   // W_ih fragment (j0)
    __syncthreads();   // all reads of pass-A done (syncthreads drains lgkmcnt)

    // ---- staging pass B: rows for j1 ----
    {
        const float4* Whh4 = (const float4*)(W_hh + (size_t)row1 * HID);
        #pragma unroll
        for (int c = 0; c < 16; ++c)
            wlds4[c * TPB + t] = Whh4[sl + 16 * c];
        wlds4[16 * TPB + t] = ((const float4*)(W_ih + (size_t)row1 * 64))[sl];
    }
    __syncthreads();   // pass-B staged

    const float4 X0  = wlds4[ 0 * TPB + t];
    const float4 X1  = wlds4[ 1 * TPB + t];
    const float4 X2  = wlds4[ 2 * TPB + t];
    const float4 X3  = wlds4[ 3 * TPB + t];
    const float4 X4  = wlds4[ 4 * TPB + t];
    const float4 X5  = wlds4[ 5 * TPB + t];
    const float4 X6  = wlds4[ 6 * TPB + t];
    const float4 X7  = wlds4[ 7 * TPB + t];
    const float4 X8  = wlds4[ 8 * TPB + t];
    const float4 X9  = wlds4[ 9 * TPB + t];
    const float4 X10 = wlds4[10 * TPB + t];
    const float4 X11 = wlds4[11 * TPB + t];
    const float4 X12 = wlds4[12 * TPB + t];
    const float4 X13 = wlds4[13 * TPB + t];
    const float4 X14 = wlds4[14 * TPB + t];
    const float4 X15 = wlds4[15 * TPB + t];
    const float4 X16 = wlds4[16 * TPB + t];   // W_ih fragment (j1)

    const float4* xin4 = (const float4*)input;
    float c0_state = 0.0f, c1_state = 0.0f;

    for (int s = 0; s < SEQ_LEN; ++s) {
        float4 x4 = xin4[s * 16 + sl];   // issue before poll (cacheable)

        // ---- poll 2 tagged slots (relaxed agent atomics, rd-flags) ----
        unsigned long long* rs = (s & 1) ? slot1 : slot0;
        const unsigned tag = (unsigned)s;
        unsigned long long v0, v1;
        bool r0 = false, r1 = false;
        do {
            if (!r0) { v0 = __hip_atomic_load(&rs[t      ], __ATOMIC_RELAXED, __HIP_MEMORY_SCOPE_AGENT);
                       r0 = ((unsigned)(v0 >> 32) == tag); }
            if (!r1) { v1 = __hip_atomic_load(&rs[t + 512], __ATOMIC_RELAXED, __HIP_MEMORY_SCOPE_AGENT);
                       r1 = ((unsigned)(v1 >> 32) == tag); }
        } while (!(r0 && r1));

        float* hsb = hs[s & 1];
        hsb[t      ] = __uint_as_float((unsigned)(v0 & 0xffffffffull));
        hsb[t + 512] = __uint_as_float((unsigned)(v1 & 0xffffffffull));

        __syncthreads();   // the ONE barrier per step: full h_s staged

        // ---- 136 FMAs: weights from REGISTERS; h chunk reads SHARED ----
        const float4* hs4 = (const float4*)hsb;
        float a0 = 0.f, a1 = 0.f, a2 = 0.f, a3 = 0.f;   // j0 gates
        float e0 = 0.f, e1 = 0.f, e2 = 0.f, e3 = 0.f;   // j1 gates
        #define FMA_CHUNK2(Wc, Xc, c, acc, ecc) { float4 h4_ = hs4[16 * (c) + sl]; \
            acc = fmaf((Wc).x, h4_.x, acc); acc = fmaf((Wc).y, h4_.y, acc);        \
            acc = fmaf((Wc).z, h4_.z, acc); acc = fmaf((Wc).w, h4_.w, acc);        \
            ecc = fmaf((Xc).x, h4_.x, ecc); ecc = fmaf((Xc).y, h4_.y, ecc);        \
            ecc = fmaf((Xc).z, h4_.z, ecc); ecc = fmaf((Xc).w, h4_.w, ecc); }
        FMA_CHUNK2(W0,  X0,  0,  a0, e0) FMA_CHUNK2(W1,  X1,  1,  a1, e1)
        FMA_CHUNK2(W2,  X2,  2,  a2, e2) FMA_CHUNK2(W3,  X3,  3,  a3, e3)
        FMA_CHUNK2(W4,  X4,  4,  a0, e0) FMA_CHUNK2(W5,  X5,  5,  a1, e1)
        FMA_CHUNK2(W6,  X6,  6,  a2, e2) FMA_CHUNK2(W7,  X7,  7,  a3, e3)
        FMA_CHUNK2(W8,  X8,  8,  a0, e0) FMA_CHUNK2(W9,  X9,  9,  a1, e1)
        FMA_CHUNK2(W10, X10, 10, a2, e2) FMA_CHUNK2(W11, X11, 11, a3, e3)
        FMA_CHUNK2(W12, X12, 12, a0, e0) FMA_CHUNK2(W13, X13, 13, a1, e1)
        FMA_CHUNK2(W14, X14, 14, a2, e2) FMA_CHUNK2(W15, X15, 15, a3, e3)
        #undef FMA_CHUNK2
        a0 = fmaf(W16.x, x4.x, a0); a1 = fmaf(W16.y, x4.y, a1);
        a2 = fmaf(W16.z, x4.z, a2); a3 = fmaf(W16.w, x4.w, a3);
        e0 = fmaf(X16.x, x4.x, e0); e1 = fmaf(X16.y, x4.y, e1);
        e2 = fmaf(X16.z, x4.z, e2); e3 = fmaf(X16.w, x4.w, e3);
        float acc = (a0 + a1) + (a2 + a3);
        float ecc = (e0 + e1) + (e2 + e3);

        // reduce across 16 lanes of the gate group (two independent trees)
        acc += __shfl_xor(acc, 1);  ecc += __shfl_xor(ecc, 1);
        acc += __shfl_xor(acc, 2);  ecc += __shfl_xor(ecc, 2);
        acc += __shfl_xor(acc, 4);  ecc += __shfl_xor(ecc, 4);
        acc += __shfl_xor(acc, 8);  ecc += __shfl_xor(ecc, 8);

        float gi0 = __shfl(acc, 0)  + bias0[0];
        float gf0 = __shfl(acc, 16) + bias0[1];
        float gg0 = __shfl(acc, 32) + bias0[2];
        float go0 = __shfl(acc, 48) + bias0[3];
        float gi1 = __shfl(ecc, 0)  + bias1[0];
        float gf1 = __shfl(ecc, 16) + bias1[1];
        float gg1 = __shfl(ecc, 32) + bias1[2];
        float go1 = __shfl(ecc, 48) + bias1[3];

        float ig0 = fast_sigmoid(gi0), ig1 = fast_sigmoid(gi1);
        float fg0 = fast_sigmoid(gf0), fg1 = fast_sigmoid(gf1);
        float cg0 = fast_tanh(gg0),    cg1 = fast_tanh(gg1);
        float og0 = fast_sigmoid(go0), og1 = fast_sigmoid(go1);
        c0_state = fmaf(fg0, c0_state, ig0 * cg0);
        c1_state = fmaf(fg1, c1_state, ig1 * cg1);
        float hn0 = og0 * fast_tanh(c0_state);
        float hn1 = og1 * fast_tanh(c1_state);

        // ---- intra-block handoff: wave w lane 0 posts its 2 tagged words ----
        const unsigned ntag = (unsigned)(s + 1);
        if (l == 0) {
            unsigned long long pv0 = ((unsigned long long)ntag << 32) |
                                     (unsigned long long)__float_as_uint(hn0);
            unsigned long long pv1 = ((unsigned long long)ntag << 32) |
                                     (unsigned long long)__float_as_uint(hn1);
            __hip_atomic_store(&pub[w],     pv0, __ATOMIC_RELAXED, __HIP_MEMORY_SCOPE_WORKGROUP);
            __hip_atomic_store(&pub[w + 8], pv1, __ATOMIC_RELAXED, __HIP_MEMORY_SCOPE_WORKGROUP);
        }
        // ---- wave 0 lanes 0..15 gather, publish one 128B (2-line) store ----
        if (w == 0 && l < HPB) {
            unsigned long long pv;
            do {
                pv = __hip_atomic_load(&pub[l], __ATOMIC_RELAXED, __HIP_MEMORY_SCOPE_WORKGROUP);
            } while ((unsigned)(pv >> 32) != ntag);
            unsigned long long* wsl = (s & 1) ? slot0 : slot1;   // buffer (s+1)&1
            __hip_atomic_store(&wsl[HPB * b + l], pv, __ATOMIC_RELAXED, __HIP_MEMORY_SCOPE_AGENT);
        }
        // no trailing barrier: hs double-buffered; slot-tag deps bound skew
    }

    // ---- final projection: h_4096 (tag 4096, even -> slot0) . W_lin + b_lin ----
    if (b == 0) {
        const unsigned tag = (unsigned)SEQ_LEN;
        unsigned long long v0, v1;
        bool r0 = false, r1 = false;
        do {
            if (!r0) { v0 = __hip_atomic_load(&slot0[t      ], __ATOMIC_RELAXED, __HIP_MEMORY_SCOPE_AGENT);
                       r0 = ((unsigned)(v0 >> 32) == tag); }
            if (!r1) { v1 = __hip_atomic_load(&slot0[t + 512], __ATOMIC_RELAXED, __HIP_MEMORY_SCOPE_AGENT);
                       r1 = ((unsigned)(v1 >> 32) == tag); }
        } while (!(r0 && r1));
        float p = __uint_as_float((unsigned)(v0 & 0xffffffffull)) * W_lin[t] +
                  __uint_as_float((unsigned)(v1 & 0xffffffffull)) * W_lin[t + 512];
        #pragma unroll
        for (int m = 32; m >= 1; m >>= 1) p += __shfl_xor(p, m);
        if (l == 0) red[w] = p;
        __syncthreads();
        if (t == 0) {
            float r = 0.f;
            #pragma unroll
            for (int k = 0; k < 8; ++k) r += red[k];
            out[0] = r + b_lin[0];
        }
    }
}

extern "C" void kernel_launch(void* const* d_in, const int* in_sizes, int n_in,
                              void* d_out, int out_size, void* d_ws, size_t ws_size,
                              hipStream_t stream) {
    const float* input = (const float*)d_in[0];
    const float* W_ih  = (const float*)d_in[1];
    const float* W_hh  = (const float*)d_in[2];
    const float* b_ih  = (const float*)d_in[3];
    const float* b_hh  = (const float*)d_in[4];
    const float* W_lin = (const float*)d_in[5];
    const float* b_lin = (const float*)d_in[6];
    float* out = (float*)d_out;
    unsigned long long* ws = (unsigned long long*)d_ws;

    hipLaunchKernelGGL(lstm_init_kernel, dim3(1), dim3(256), 0, stream, ws);

    void* args[] = { (void*)&input, (void*)&W_ih, (void*)&W_hh, (void*)&b_ih,
                     (void*)&b_hh, (void*)&W_lin, (void*)&b_lin, (void*)&out, (void*)&ws };
    (void)hipLaunchCooperativeKernel((void*)lstm_persistent_kernel, dim3(NBLK), dim3(TPB),
                                     args, 0, stream);
}

// Round 9
// 8034.732 us; speedup vs baseline: 1.1377x; 1.1377x over previous
//
#include <hip/hip_runtime.h>

// LSTM: S=4096, I=64, H=1024, O=1, fp32.
// Persistent cooperative kernel, 128 blocks x 512 threads (r6 skeleton).
// FINAL RESTORE of the twice-verified baseline (8030.7us / 8039.0us, absmax 0).
// Session record — every perturbation direction regressed or failed:
//   r1 inbox fan-out (+18%) | r2 wave dataflow (+103%) | r3 depth-2 poll (+13%)
//   r4 chunk flags (+25%)   | r5 tag/data decouple (+171%)
//   r7 64-block rescale (+13%) | r8 single-XCD sc0 gambit (launch failure)
// Protocol (sharp local optimum):
//   - tagged 8-byte atoms {tag:32|h_bits:32}, relaxed agent-scope atomics
//   - tagged parity double buffer, zero fences
//   - ONE in-flight conditional poll per address (min MALL request pressure)
//   - ONE __syncthreads per step (cheapest max-of-arrivals coupling)
//   - wave-0 LDS gather + ONE coalesced 64B line publish per block
//     (WRITE_SIZE must stay 32768 KB)
//   - weights in NAMED VGPRs via LDS bounce (LDS-sourced reads are not
//     remat-able -> RA keeps them resident)
// Ceiling: 4096 serial cross-XCD broadcasts; step ~= store-visibility +
// poll-detect + max-of-128 arrival jitter ~= 4000-4700 cyc ~= 1.96us. No
// HIP-visible mechanism found (7 attempts) that shortens the chain.

#define SEQ_LEN 4096
#define HID 1024
#define NBLK 128
#define TPB 512
#define HPB 8      // h-indices per block (one per wave)

__device__ __forceinline__ float fast_sigmoid(float x) {
    return __builtin_amdgcn_rcpf(1.0f + __builtin_amdgcn_exp2f(-1.4426950408889634f * x));
}
__device__ __forceinline__ float fast_tanh(float x) {
    return fmaf(-2.0f, __builtin_amdgcn_rcpf(1.0f + __builtin_amdgcn_exp2f(2.8853900817779268f * x)), 1.0f);
}

// ws: unsigned long long slots[2][1024]. {tag:32 | fp32 bits}. Zero-init:
// buffer0 tag0/val0 == h_0 = 0 (correct); buffer1 receives odd tags.
__global__ void lstm_init_kernel(unsigned long long* ws) {
    int t = threadIdx.x;
    #pragma unroll
    for (int k = 0; k < 8; ++k) ws[t + 256 * k] = 0ull;
}

__global__ __launch_bounds__(TPB, 1) void lstm_persistent_kernel(
    const float* __restrict__ input,   // [4096][64]
    const float* __restrict__ W_ih,    // [4096][64]
    const float* __restrict__ W_hh,    // [4096][1024]
    const float* __restrict__ b_ih,    // [4096]
    const float* __restrict__ b_hh,    // [4096]
    const float* __restrict__ W_lin,   // [1][1024]
    const float* __restrict__ b_lin,   // [1]
    float* __restrict__ out,           // [1]
    unsigned long long* __restrict__ ws)
{
    const int t   = threadIdx.x;
    const int b   = blockIdx.x;
    const int w   = t >> 6;      // wave in block (0..7)
    const int l   = t & 63;      // lane
    const int grp = l >> 4;      // gate q (i,f,g,o)
    const int sl  = l & 15;      // sub-lane within gate group
    const int j   = HPB * b + w; // owned h index
    const int row = grp * HID + j;

    unsigned long long* slot0 = ws;          // even tags
    unsigned long long* slot1 = ws + HID;    // odd tags

    __shared__ float4 wlds4[17 * TPB];       // 136 KB weight staging
    __shared__ float  hs[2][HID];            // double-buffered h (8 KB)
    __shared__ unsigned long long pub[HPB];  // tagged intra-block handoff
    __shared__ float  red[HPB];

    // ---- stage this block's 32 gate-rows into LDS ----
    {
        const float4* Whh4 = (const float4*)(W_hh + (size_t)row * HID);
        #pragma unroll
        for (int c = 0; c < 16; ++c)
            wlds4[c * TPB + t] = Whh4[sl + 16 * c];     // W_hh[row][64c+4sl..+3]
        wlds4[16 * TPB + t] = ((const float4*)(W_ih + (size_t)row * 64))[sl];
    }
    float bias[4];
    #pragma unroll
    for (int q = 0; q < 4; ++q) bias[q] = b_ih[q * HID + j] + b_hh[q * HID + j];
    if (t < HPB) pub[t] = 0ull;
    __syncthreads();   // weights staged, pub initialized

    // ---- LDS -> named registers (NOT remat-able: RA must keep in VGPRs) ----
    const float4 W0  = wlds4[ 0 * TPB + t];
    const float4 W1  = wlds4[ 1 * TPB + t];
    const float4 W2  = wlds4[ 2 * TPB + t];
    const float4 W3  = wlds4[ 3 * TPB + t];
    const float4 W4  = wlds4[ 4 * TPB + t];
    const float4 W5  = wlds4[ 5 * TPB + t];
    const float4 W6  = wlds4[ 6 * TPB + t];
    const float4 W7  = wlds4[ 7 * TPB + t];
    const float4 W8  = wlds4[ 8 * TPB + t];
    const float4 W9  = wlds4[ 9 * TPB + t];
    const float4 W10 = wlds4[10 * TPB + t];
    const float4 W11 = wlds4[11 * TPB + t];
    const float4 W12 = wlds4[12 * TPB + t];
    const float4 W13 = wlds4[13 * TPB + t];
    const float4 W14 = wlds4[14 * TPB + t];
    const float4 W15 = wlds4[15 * TPB + t];
    const float4 W16 = wlds4[16 * TPB + t];   // W_ih fragment

    const float4* xin4 = (const float4*)input;
    float c_state = 0.0f;

    for (int s = 0; s < SEQ_LEN; ++s) {
        float4 x4 = xin4[s * 16 + sl];   // issue before poll (cacheable)

        // ---- poll 2 tagged slots (relaxed agent atomics, rd-flags) ----
        unsigned long long* rs = (s & 1) ? slot1 : slot0;
        const unsigned tag = (unsigned)s;
        unsigned long long v0, v1;
        bool r0 = false, r1 = false;
        do {
            if (!r0) { v0 = __hip_atomic_load(&rs[t      ], __ATOMIC_RELAXED, __HIP_MEMORY_SCOPE_AGENT);
                       r0 = ((unsigned)(v0 >> 32) == tag); }
            if (!r1) { v1 = __hip_atomic_load(&rs[t + 512], __ATOMIC_RELAXED, __HIP_MEMORY_SCOPE_AGENT);
                       r1 = ((unsigned)(v1 >> 32) == tag); }
        } while (!(r0 && r1));

        float* hsb = hs[s & 1];
        hsb[t      ] = __uint_as_float((unsigned)(v0 & 0xffffffffull));
        hsb[t + 512] = __uint_as_float((unsigned)(v1 & 0xffffffffull));

        __syncthreads();   // the ONE barrier per step: full h_s staged

        // ---- 68 FMAs: weights from REGISTERS, h broadcast-read from LDS ----
        const float4* hs4 = (const float4*)hsb;
        float a0 = 0.f, a1 = 0.f, a2 = 0.f, a3 = 0.f;
        #define FMA_CHUNK(Wc, c, acc) { float4 h4_ = hs4[16 * (c) + sl];      \
            acc = fmaf((Wc).x, h4_.x, acc); acc = fmaf((Wc).y, h4_.y, acc);   \
            acc = fmaf((Wc).z, h4_.z, acc); acc = fmaf((Wc).w, h4_.w, acc); }
        FMA_CHUNK(W0,  0, a0) FMA_CHUNK(W1,  1, a1)
        FMA_CHUNK(W2,  2, a2) FMA_CHUNK(W3,  3, a3)
        FMA_CHUNK(W4,  4, a0) FMA_CHUNK(W5,  5, a1)
        FMA_CHUNK(W6,  6, a2) FMA_CHUNK(W7,  7, a3)
        FMA_CHUNK(W8,  8, a0) FMA_CHUNK(W9,  9, a1)
        FMA_CHUNK(W10, 10, a2) FMA_CHUNK(W11, 11, a3)
        FMA_CHUNK(W12, 12, a0) FMA_CHUNK(W13, 13, a1)
        FMA_CHUNK(W14, 14, a2) FMA_CHUNK(W15, 15, a3)
        #undef FMA_CHUNK
        a0 = fmaf(W16.x, x4.x, a0); a1 = fmaf(W16.y, x4.y, a1);
        a2 = fmaf(W16.z, x4.z, a2); a3 = fmaf(W16.w, x4.w, a3);
        float acc = (a0 + a1) + (a2 + a3);

        // reduce across 16 lanes of the gate group
        acc += __shfl_xor(acc, 1);
        acc += __shfl_xor(acc, 2);
        acc += __shfl_xor(acc, 4);
        acc += __shfl_xor(acc, 8);

        float gi = __shfl(acc, 0)  + bias[0];
        float gf = __shfl(acc, 16) + bias[1];
        float gg = __shfl(acc, 32) + bias[2];
        float go = __shfl(acc, 48) + bias[3];

        float ig = fast_sigmoid(gi);
        float fg = fast_sigmoid(gf);
        float cg = fast_tanh(gg);
        float og = fast_sigmoid(go);
        c_state  = fmaf(fg, c_state, ig * cg);
        float hn = og * fast_tanh(c_state);

        // ---- intra-block handoff: wave w lane 0 posts tagged hn to LDS ----
        const unsigned ntag = (unsigned)(s + 1);
        if (l == 0) {
            unsigned long long pv = ((unsigned long long)ntag << 32) |
                                    (unsigned long long)__float_as_uint(hn);
            __hip_atomic_store(&pub[w], pv, __ATOMIC_RELAXED, __HIP_MEMORY_SCOPE_WORKGROUP);
        }
        // ---- wave 0 lanes 0..7 gather the 8 words, publish one 64B line ----
        if (w == 0 && l < HPB) {
            unsigned long long pv;
            do {
                pv = __hip_atomic_load(&pub[l], __ATOMIC_RELAXED, __HIP_MEMORY_SCOPE_WORKGROUP);
            } while ((unsigned)(pv >> 32) != ntag);
            unsigned long long* wsl = (s & 1) ? slot0 : slot1;   // buffer (s+1)&1
            __hip_atomic_store(&wsl[HPB * b + l], pv, __ATOMIC_RELAXED, __HIP_MEMORY_SCOPE_AGENT);
        }
        // no trailing barrier: hs double-buffered; slot-tag deps bound skew
    }

    // ---- final projection: h_4096 (tag 4096, even -> slot0) . W_lin + b_lin ----
    if (b == 0) {
        const unsigned tag = (unsigned)SEQ_LEN;
        unsigned long long v0, v1;
        bool r0 = false, r1 = false;
        do {
            if (!r0) { v0 = __hip_atomic_load(&slot0[t      ], __ATOMIC_RELAXED, __HIP_MEMORY_SCOPE_AGENT);
                       r0 = ((unsigned)(v0 >> 32) == tag); }
            if (!r1) { v1 = __hip_atomic_load(&slot0[t + 512], __ATOMIC_RELAXED, __HIP_MEMORY_SCOPE_AGENT);
                       r1 = ((unsigned)(v1 >> 32) == tag); }
        } while (!(r0 && r1));
        float p = __uint_as_float((unsigned)(v0 & 0xffffffffull)) * W_lin[t] +
                  __uint_as_float((unsigned)(v1 & 0xffffffffull)) * W_lin[t + 512];
        #pragma unroll
        for (int m = 32; m >= 1; m >>= 1) p += __shfl_xor(p, m);
        if (l == 0) red[w] = p;
        __syncthreads();
        if (t == 0) {
            float r = 0.f;
            #pragma unroll
            for (int k = 0; k < HPB; ++k) r += red[k];
            out[0] = r + b_lin[0];
        }
    }
}

extern "C" void kernel_launch(void* const* d_in, const int* in_sizes, int n_in,
                              void* d_out, int out_size, void* d_ws, size_t ws_size,
                              hipStream_t stream) {
    const float* input = (const float*)d_in[0];
    const float* W_ih  = (const float*)d_in[1];
    const float* W_hh  = (const float*)d_in[2];
    const float* b_ih  = (const float*)d_in[3];
    const float* b_hh  = (const float*)d_in[4];
    const float* W_lin = (const float*)d_in[5];
    const float* b_lin = (const float*)d_in[6];
    float* out = (float*)d_out;
    unsigned long long* ws = (unsigned long long*)d_ws;

    hipLaunchKernelGGL(lstm_init_kernel, dim3(1), dim3(256), 0, stream, ws);

    void* args[] = { (void*)&input, (void*)&W_ih, (void*)&W_hh, (void*)&b_ih,
                     (void*)&b_hh, (void*)&W_lin, (void*)&b_lin, (void*)&out, (void*)&ws };
    (void)hipLaunchCooperativeKernel((void*)lstm_persistent_kernel, dim3(NBLK), dim3(TPB),
                                     args, 0, stream);
}